// Round 4
// baseline (732.471 us; speedup 1.0000x reference)
//
#include <hip/hip_runtime.h>
#include <stdint.h>

// Problem constants (B=4, S=1536, D=2048, H=16, hd=128)
#define BB 4
#define SS 1536
#define DD 2048
#define HH 16
#define HD 128
#define BS (BB * SS)        // 6144 rows
#define N3 (3 * DD)         // 6144

typedef __bf16 bf16x8 __attribute__((ext_vector_type(8)));
typedef float f32x4 __attribute__((ext_vector_type(4)));

__device__ __forceinline__ void async16(const void* g, void* lds) {
  __builtin_amdgcn_global_load_lds(
      (const __attribute__((address_space(1))) unsigned int*)g,
      (__attribute__((address_space(3))) unsigned int*)lds, 16, 0, 0);
}

__global__ __launch_bounds__(256) void cast_bf16_kernel(
    const float* __restrict__ in, __bf16* __restrict__ out) {
  long i = ((long)blockIdx.x * 256 + threadIdx.x) * 8;
  float4 a = *(const float4*)(in + i);
  float4 b = *(const float4*)(in + i + 4);
  bf16x8 o;
  o[0] = (__bf16)a.x; o[1] = (__bf16)a.y; o[2] = (__bf16)a.z; o[3] = (__bf16)a.w;
  o[4] = (__bf16)b.x; o[5] = (__bf16)b.y; o[6] = (__bf16)b.z; o[7] = (__bf16)b.w;
  *(bf16x8*)(out + i) = o;
}

__global__ __launch_bounds__(256) void transpose_cast_kernel(
    const float* __restrict__ in, __bf16* __restrict__ out, int R, int C) {
  __shared__ __bf16 t[32][33];
  int tx = threadIdx.x & 31, ty = threadIdx.x >> 5;  // 32 x 8
  long r0 = (long)blockIdx.y * 32, c0 = (long)blockIdx.x * 32;
#pragma unroll
  for (int i = 0; i < 4; ++i)
    t[ty + i * 8][tx] = (__bf16)in[(r0 + ty + i * 8) * C + c0 + tx];
  __syncthreads();
#pragma unroll
  for (int i = 0; i < 4; ++i)
    out[(c0 + ty + i * 8) * R + r0 + tx] = t[tx][ty + i * 8];
}

// ---------------------------------------------------------------------------
// GEMM with XOR-swizzled LDS (chunk c of row r at slot c ^ ((r>>1)&3)).
// ---------------------------------------------------------------------------
__device__ __forceinline__ void store_val(__bf16* p, float v) { *p = (__bf16)v; }
__device__ __forceinline__ void store_val(float* p, float v) { *p = v; }

template <typename OutT>
__global__ __launch_bounds__(256, 2) void gemm_bt_kernel(
    const __bf16* __restrict__ A, const __bf16* __restrict__ Bt,
    const float* __restrict__ bias, OutT* __restrict__ C,
    int M, int N, int K) {
  __shared__ __attribute__((aligned(16))) __bf16 sA[128 * 32];
  __shared__ __attribute__((aligned(16))) __bf16 sB[128 * 32];
  const int tid = threadIdx.x;
  const int wave = tid >> 6, lane = tid & 63;
  const int quad = lane >> 4, l15 = lane & 15;
  const int bm = blockIdx.y * 128, bn = blockIdx.x * 128;
  const int wr = (wave >> 1) * 64, wc = (wave & 1) * 64;

  const int srow = lane >> 2;
  const int scol = ((lane & 3) ^ ((lane >> 3) & 3)) * 8;  // swizzled source
  const __bf16* Ap = A + (long)(bm + wave * 32 + srow) * K + scol;
  const __bf16* Bp = Bt + (long)(bn + wave * 32 + srow) * K + scol;
  __bf16* sAw = &sA[wave * 32 * 32];
  __bf16* sBw = &sB[wave * 32 * 32];

  const int achunk = (quad ^ ((l15 >> 1) & 3)) * 8;  // swizzled frag read

  f32x4 acc[4][4] = {};

  for (int k0 = 0; k0 < K; k0 += 32) {
    __syncthreads();
    async16(Ap + k0, sAw);
    async16(Ap + k0 + (long)16 * K, sAw + 16 * 32);
    async16(Bp + k0, sBw);
    async16(Bp + k0 + (long)16 * K, sBw + 16 * 32);
    __syncthreads();
    bf16x8 af[4], bfr[4];
#pragma unroll
    for (int i = 0; i < 4; ++i)
      af[i] = *(const bf16x8*)&sA[(wr + i * 16 + l15) * 32 + achunk];
#pragma unroll
    for (int i = 0; i < 4; ++i)
      bfr[i] = *(const bf16x8*)&sB[(wc + i * 16 + l15) * 32 + achunk];
#pragma unroll
    for (int i = 0; i < 4; ++i)
#pragma unroll
      for (int j = 0; j < 4; ++j)
        acc[i][j] = __builtin_amdgcn_mfma_f32_16x16x32_bf16(af[i], bfr[j],
                                                            acc[i][j], 0, 0, 0);
  }

#pragma unroll
  for (int i = 0; i < 4; ++i) {
    int row0 = bm + wr + i * 16 + quad * 4;
#pragma unroll
    for (int j = 0; j < 4; ++j) {
      int col = bn + wc + j * 16 + l15;
      float bv = bias[col];
#pragma unroll
      for (int r = 0; r < 4; ++r)
        store_val(&C[(long)(row0 + r) * N + col], acc[i][j][r] + bv);
    }
  }
}

__global__ __launch_bounds__(256) void rmsnorm_kernel(
    __bf16* __restrict__ qkv, const float* __restrict__ qw,
    const float* __restrict__ kw) {
  const int r = blockIdx.x;
  const bool isQ = r < BS;
  const int row = isQ ? r : r - BS;
  __bf16* p = qkv + (long)row * N3 + (isQ ? 0 : DD);
  const float* w = isQ ? qw : kw;
  const float extra = isQ ? (0.0883883476483184f * 1.44269504088896f) : 1.0f;
  const int t = threadIdx.x;

  bf16x8 v = *(const bf16x8*)(p + t * 8);
  float f[8];
  float s = 0.f;
#pragma unroll
  for (int i = 0; i < 8; ++i) { f[i] = (float)v[i]; s += f[i] * f[i]; }
#pragma unroll
  for (int off = 32; off > 0; off >>= 1) s += __shfl_xor(s, off, 64);
  __shared__ float red[4];
  if ((t & 63) == 0) red[t >> 6] = s;
  __syncthreads();
  float tot = red[0] + red[1] + red[2] + red[3];
  float rs = rsqrtf(tot * (1.0f / (float)DD) + 1e-6f) * extra;
  bf16x8 o;
#pragma unroll
  for (int i = 0; i < 8; ++i) o[i] = (__bf16)(f[i] * rs * w[t * 8 + i]);
  *(bf16x8*)(p + t * 8) = o;
}

__global__ __launch_bounds__(256) void transpose_v_kernel(
    const __bf16* __restrict__ qkv, __bf16* __restrict__ vt) {
  __shared__ __bf16 t[32][33];
  const int bh = blockIdx.z, b = bh >> 4, h = bh & 15;
  const int s0 = blockIdx.x * 32, d0 = blockIdx.y * 32;
  const int tx = threadIdx.x & 31, ty = threadIdx.x >> 5;
#pragma unroll
  for (int i = 0; i < 4; ++i) {
    int s = s0 + ty + i * 8;
    t[ty + i * 8][tx] =
        qkv[(long)(b * SS + s) * N3 + 2 * DD + h * HD + d0 + tx];
  }
  __syncthreads();
#pragma unroll
  for (int i = 0; i < 4; ++i) {
    int d = d0 + ty + i * 8;
    vt[((long)bh * HD + d) * SS + s0 + tx] = t[tx][ty + i * 8];
  }
}

// ---------------------------------------------------------------------------
// Flash attention v4, causal. grid (S/128, B*H), 4 INDEPENDENT waves (no
// __syncthreads in the kernel). Wave owns 32 q-rows (2 row-tiles). K and V^T
// fragments are loaded DIRECTLY global->VGPR (bf16x8 per lane); duplicate
// reads across waves hit L2/L3. No LDS staging -> no barrier drains; compiler
// interleaves MFMA with vmcnt(N) loads (AITER-style). Only LDS use: the
// wave-private P C-layout -> A-layout round-trip (lgkm-ordered, swizzled).
// Fixed-reference softmax: p = exp2(s) raw; scale cancels in O/l.
// Per-wave exact tile count: jn = 2qi+1+(wave>>1); mask only on last tile.
// ---------------------------------------------------------------------------
__global__ __launch_bounds__(256, 2) void attn_kernel(
    const __bf16* __restrict__ qkv, const __bf16* __restrict__ vt,
    __bf16* __restrict__ O) {
  __shared__ __attribute__((aligned(16))) __bf16 sP[4][32 * 64]; // 16 KB

  const int qi = gridDim.x - 1 - blockIdx.x, bh = blockIdx.y;
  const int b = bh >> 4, h = bh & 15;
  const int tid = threadIdx.x, wave = tid >> 6, lane = tid & 63;
  const int quad = lane >> 4, l15 = lane & 15;
  const int sw3 = l15 & 7;

  const long rowQ0 = (long)(b * SS + qi * 128);   // block's first q row
  const int qrow0 = qi * 128 + wave * 32;         // wave's first q row (in S)
  // per-lane K/V base pointers (row = l15-th of a 16-row tile)
  const __bf16* klane =
      qkv + ((long)(b * SS) + l15) * N3 + DD + h * HD + quad * 8;
  const __bf16* vlane = vt + ((long)bh * HD + l15) * SS + quad * 8;

  // Q fragments in registers: qf[mt][kk] for row-tile mt (rows +mt*16)
  bf16x8 qf[2][4];
#pragma unroll
  for (int mt = 0; mt < 2; ++mt) {
    const __bf16* qp =
        qkv + (rowQ0 + wave * 32 + mt * 16 + l15) * N3 + h * HD + quad * 8;
#pragma unroll
    for (int kk = 0; kk < 4; ++kk) qf[mt][kk] = *(const bf16x8*)(qp + kk * 32);
  }

  f32x4 o_acc[2][8] = {};
  float l_acc[2][4] = {};

  __bf16* sPw = &sP[wave][0];
  const int jn = 2 * qi + 1 + (wave >> 1);  // exact per-wave tile count

  for (int j = 0; j < jn; ++j) {
    const bool lastTile = (j == jn - 1);

    // ---- S = Q K^T : K B-frags direct from global (2 chunks of 8 loads) ----
    f32x4 sacc[2][4];
#pragma unroll
    for (int nt = 0; nt < 4; ++nt) {
      sacc[0][nt] = (f32x4){0.f, 0.f, 0.f, 0.f};
      sacc[1][nt] = (f32x4){0.f, 0.f, 0.f, 0.f};
    }
#pragma unroll
    for (int kc = 0; kc < 2; ++kc) {  // kk = kc*2 .. kc*2+1
      bf16x8 bk[2][4];
#pragma unroll
      for (int kk = 0; kk < 2; ++kk)
#pragma unroll
        for (int nt = 0; nt < 4; ++nt)
          bk[kk][nt] = *(const bf16x8*)(klane +
              (long)(j * 64 + nt * 16) * N3 + (kc * 2 + kk) * 32);
#pragma unroll
      for (int kk = 0; kk < 2; ++kk)
#pragma unroll
        for (int nt = 0; nt < 4; ++nt) {
          sacc[0][nt] = __builtin_amdgcn_mfma_f32_16x16x32_bf16(
              qf[0][kc * 2 + kk], bk[kk][nt], sacc[0][nt], 0, 0, 0);
          sacc[1][nt] = __builtin_amdgcn_mfma_f32_16x16x32_bf16(
              qf[1][kc * 2 + kk], bk[kk][nt], sacc[1][nt], 0, 0, 0);
        }
    }
    if (lastTile) {  // causal mask (only the final tile straddles the diag)
#pragma unroll
      for (int mt = 0; mt < 2; ++mt) {
        int rowg0 = qrow0 + mt * 16 + quad * 4;
#pragma unroll
        for (int nt = 0; nt < 4; ++nt) {
          int colg = j * 64 + nt * 16 + l15;
#pragma unroll
          for (int r = 0; r < 4; ++r)
            if (colg > rowg0 + r) sacc[mt][nt][r] = -1e30f;
        }
      }
    }
    // ---- p = exp2(s) -> sP (wave-private), accumulate l per lane ----
#pragma unroll
    for (int mt = 0; mt < 2; ++mt) {
#pragma unroll
      for (int nt = 0; nt < 4; ++nt) {
#pragma unroll
        for (int r = 0; r < 4; ++r) {
          float pv = exp2f(sacc[mt][nt][r]);
          l_acc[mt][r] += pv;
          int prow = mt * 16 + quad * 4 + r;
          int pcol = nt * 16 + l15;
          sPw[prow * 64 + (((pcol >> 3) ^ (prow & 7)) * 8) + (pcol & 7)] =
              (__bf16)pv;
        }
      }
    }
    // ---- O += P V : V B-frags direct from global, ap from LDS ----
#pragma unroll
    for (int kk = 0; kk < 2; ++kk) {
      bf16x8 bv[8];
#pragma unroll
      for (int dt = 0; dt < 8; ++dt)
        bv[dt] = *(const bf16x8*)(vlane + (long)(dt * 16) * SS +
                                  j * 64 + kk * 32);
      bf16x8 ap0 = *(const bf16x8*)
          &sPw[l15 * 64 + (((kk * 4 + quad) ^ sw3) * 8)];
      bf16x8 ap1 = *(const bf16x8*)
          &sPw[(16 + l15) * 64 + (((kk * 4 + quad) ^ sw3) * 8)];
#pragma unroll
      for (int dt = 0; dt < 8; ++dt) {
        o_acc[0][dt] = __builtin_amdgcn_mfma_f32_16x16x32_bf16(
            ap0, bv[dt], o_acc[0][dt], 0, 0, 0);
        o_acc[1][dt] = __builtin_amdgcn_mfma_f32_16x16x32_bf16(
            ap1, bv[dt], o_acc[1][dt], 0, 0, 0);
      }
    }
  }

  // final l reduction across the 16 lanes of each quad-row, then write O
#pragma unroll
  for (int mt = 0; mt < 2; ++mt) {
    __bf16* obase = O + (rowQ0 + wave * 32 + mt * 16 + quad * 4) * DD + h * HD;
#pragma unroll
    for (int r = 0; r < 4; ++r) {
      float l = l_acc[mt][r];
#pragma unroll
      for (int off = 1; off < 16; off <<= 1) l += __shfl_xor(l, off, 64);
      float inv = 1.0f / l;
#pragma unroll
      for (int dt = 0; dt < 8; ++dt)
        obase[(long)r * DD + dt * 16 + l15] = (__bf16)(o_acc[mt][dt][r] * inv);
    }
  }
}

extern "C" void kernel_launch(void* const* d_in, const int* in_sizes, int n_in,
                              void* d_out, int out_size, void* d_ws,
                              size_t ws_size, hipStream_t stream) {
  const float* x      = (const float*)d_in[0];
  const float* w_qkv  = (const float*)d_in[1];
  const float* b_qkv  = (const float*)d_in[2];
  const float* q_ln_w = (const float*)d_in[3];
  const float* k_ln_w = (const float*)d_in[4];
  const float* w_out  = (const float*)d_in[5];
  const float* b_out  = (const float*)d_in[6];
  float* out = (float*)d_out;

  char* w = (char*)d_ws;
  __bf16* xb    = (__bf16*)(w);
  __bf16* wqkvT = (__bf16*)(w + 25165824L);
  __bf16* woutT = (__bf16*)(w + 50331648L);
  __bf16* qkvb  = (__bf16*)(w + 58720256L);
  __bf16* vtb   = (__bf16*)(w + 134217728L);
  __bf16* atto  = xb;

  cast_bf16_kernel<<<dim3(BS * DD / 2048), 256, 0, stream>>>(x, xb);
  transpose_cast_kernel<<<dim3(N3 / 32, DD / 32), 256, 0, stream>>>(
      w_qkv, wqkvT, DD, N3);
  transpose_cast_kernel<<<dim3(DD / 32, DD / 32), 256, 0, stream>>>(
      w_out, woutT, DD, DD);

  gemm_bt_kernel<__bf16><<<dim3(N3 / 128, BS / 128), 256, 0, stream>>>(
      xb, wqkvT, b_qkv, qkvb, BS, N3, DD);

  rmsnorm_kernel<<<dim3(2 * BS), 256, 0, stream>>>(qkvb, q_ln_w, k_ln_w);

  transpose_v_kernel<<<dim3(SS / 32, HD / 32, BB * HH), 256, 0, stream>>>(
      qkvb, vtb);

  attn_kernel<<<dim3(SS / 128, BB * HH), 256, 0, stream>>>(qkvb, vtb, atto);

  gemm_bt_kernel<float><<<dim3(DD / 128, BS / 128), 256, 0, stream>>>(
      atto, woutT, b_out, out, BS, DD, DD);
}

// Round 5
// 536.549 us; speedup vs baseline: 1.3652x; 1.3652x over previous
//
#include <hip/hip_runtime.h>
#include <stdint.h>

// Problem constants (B=4, S=1536, D=2048, H=16, hd=128)
#define BB 4
#define SS 1536
#define DD 2048
#define HH 16
#define HD 128
#define BS (BB * SS)        // 6144 rows
#define N3 (3 * DD)         // 6144

typedef __bf16 bf16x8 __attribute__((ext_vector_type(8)));
typedef float f32x4 __attribute__((ext_vector_type(4)));

__device__ __forceinline__ void async16(const void* g, void* lds) {
  __builtin_amdgcn_global_load_lds(
      (const __attribute__((address_space(1))) unsigned int*)g,
      (__attribute__((address_space(3))) unsigned int*)lds, 16, 0, 0);
}

__global__ __launch_bounds__(256) void cast_bf16_kernel(
    const float* __restrict__ in, __bf16* __restrict__ out) {
  long i = ((long)blockIdx.x * 256 + threadIdx.x) * 8;
  float4 a = *(const float4*)(in + i);
  float4 b = *(const float4*)(in + i + 4);
  bf16x8 o;
  o[0] = (__bf16)a.x; o[1] = (__bf16)a.y; o[2] = (__bf16)a.z; o[3] = (__bf16)a.w;
  o[4] = (__bf16)b.x; o[5] = (__bf16)b.y; o[6] = (__bf16)b.z; o[7] = (__bf16)b.w;
  *(bf16x8*)(out + i) = o;
}

__global__ __launch_bounds__(256) void transpose_cast_kernel(
    const float* __restrict__ in, __bf16* __restrict__ out, int R, int C) {
  __shared__ __bf16 t[32][33];
  int tx = threadIdx.x & 31, ty = threadIdx.x >> 5;  // 32 x 8
  long r0 = (long)blockIdx.y * 32, c0 = (long)blockIdx.x * 32;
#pragma unroll
  for (int i = 0; i < 4; ++i)
    t[ty + i * 8][tx] = (__bf16)in[(r0 + ty + i * 8) * C + c0 + tx];
  __syncthreads();
#pragma unroll
  for (int i = 0; i < 4; ++i)
    out[(c0 + ty + i * 8) * R + r0 + tx] = t[tx][ty + i * 8];
}

// ---------------------------------------------------------------------------
// GEMM with XOR-swizzled LDS (chunk c of row r at slot c ^ ((r>>1)&3)).
// ---------------------------------------------------------------------------
__device__ __forceinline__ void store_val(__bf16* p, float v) { *p = (__bf16)v; }
__device__ __forceinline__ void store_val(float* p, float v) { *p = v; }

template <typename OutT>
__global__ __launch_bounds__(256, 2) void gemm_bt_kernel(
    const __bf16* __restrict__ A, const __bf16* __restrict__ Bt,
    const float* __restrict__ bias, OutT* __restrict__ C,
    int M, int N, int K) {
  __shared__ __attribute__((aligned(16))) __bf16 sA[128 * 32];
  __shared__ __attribute__((aligned(16))) __bf16 sB[128 * 32];
  const int tid = threadIdx.x;
  const int wave = tid >> 6, lane = tid & 63;
  const int quad = lane >> 4, l15 = lane & 15;
  const int bm = blockIdx.y * 128, bn = blockIdx.x * 128;
  const int wr = (wave >> 1) * 64, wc = (wave & 1) * 64;

  const int srow = lane >> 2;
  const int scol = ((lane & 3) ^ ((lane >> 3) & 3)) * 8;  // swizzled source
  const __bf16* Ap = A + (long)(bm + wave * 32 + srow) * K + scol;
  const __bf16* Bp = Bt + (long)(bn + wave * 32 + srow) * K + scol;
  __bf16* sAw = &sA[wave * 32 * 32];
  __bf16* sBw = &sB[wave * 32 * 32];

  const int achunk = (quad ^ ((l15 >> 1) & 3)) * 8;  // swizzled frag read

  f32x4 acc[4][4] = {};

  for (int k0 = 0; k0 < K; k0 += 32) {
    __syncthreads();
    async16(Ap + k0, sAw);
    async16(Ap + k0 + (long)16 * K, sAw + 16 * 32);
    async16(Bp + k0, sBw);
    async16(Bp + k0 + (long)16 * K, sBw + 16 * 32);
    __syncthreads();
    bf16x8 af[4], bfr[4];
#pragma unroll
    for (int i = 0; i < 4; ++i)
      af[i] = *(const bf16x8*)&sA[(wr + i * 16 + l15) * 32 + achunk];
#pragma unroll
    for (int i = 0; i < 4; ++i)
      bfr[i] = *(const bf16x8*)&sB[(wc + i * 16 + l15) * 32 + achunk];
#pragma unroll
    for (int i = 0; i < 4; ++i)
#pragma unroll
      for (int j = 0; j < 4; ++j)
        acc[i][j] = __builtin_amdgcn_mfma_f32_16x16x32_bf16(af[i], bfr[j],
                                                            acc[i][j], 0, 0, 0);
  }

#pragma unroll
  for (int i = 0; i < 4; ++i) {
    int row0 = bm + wr + i * 16 + quad * 4;
#pragma unroll
    for (int j = 0; j < 4; ++j) {
      int col = bn + wc + j * 16 + l15;
      float bv = bias[col];
#pragma unroll
      for (int r = 0; r < 4; ++r)
        store_val(&C[(long)(row0 + r) * N + col], acc[i][j][r] + bv);
    }
  }
}

__global__ __launch_bounds__(256) void rmsnorm_kernel(
    __bf16* __restrict__ qkv, const float* __restrict__ qw,
    const float* __restrict__ kw) {
  const int r = blockIdx.x;
  const bool isQ = r < BS;
  const int row = isQ ? r : r - BS;
  __bf16* p = qkv + (long)row * N3 + (isQ ? 0 : DD);
  const float* w = isQ ? qw : kw;
  const float extra = isQ ? (0.0883883476483184f * 1.44269504088896f) : 1.0f;
  const int t = threadIdx.x;

  bf16x8 v = *(const bf16x8*)(p + t * 8);
  float f[8];
  float s = 0.f;
#pragma unroll
  for (int i = 0; i < 8; ++i) { f[i] = (float)v[i]; s += f[i] * f[i]; }
#pragma unroll
  for (int off = 32; off > 0; off >>= 1) s += __shfl_xor(s, off, 64);
  __shared__ float red[4];
  if ((t & 63) == 0) red[t >> 6] = s;
  __syncthreads();
  float tot = red[0] + red[1] + red[2] + red[3];
  float rs = rsqrtf(tot * (1.0f / (float)DD) + 1e-6f) * extra;
  bf16x8 o;
#pragma unroll
  for (int i = 0; i < 8; ++i) o[i] = (__bf16)(f[i] * rs * w[t * 8 + i]);
  *(bf16x8*)(p + t * 8) = o;
}

__global__ __launch_bounds__(256) void transpose_v_kernel(
    const __bf16* __restrict__ qkv, __bf16* __restrict__ vt) {
  __shared__ __bf16 t[32][33];
  const int bh = blockIdx.z, b = bh >> 4, h = bh & 15;
  const int s0 = blockIdx.x * 32, d0 = blockIdx.y * 32;
  const int tx = threadIdx.x & 31, ty = threadIdx.x >> 5;
#pragma unroll
  for (int i = 0; i < 4; ++i) {
    int s = s0 + ty + i * 8;
    t[ty + i * 8][tx] =
        qkv[(long)(b * SS + s) * N3 + 2 * DD + h * HD + d0 + tx];
  }
  __syncthreads();
#pragma unroll
  for (int i = 0; i < 4; ++i) {
    int d = d0 + ty + i * 8;
    vt[((long)bh * HD + d) * SS + s0 + tx] = t[tx][ty + i * 8];
  }
}

// ---------------------------------------------------------------------------
// Flash attention v5, causal. grid (S/128, B*H), 4 waves; wave owns 32 q-rows.
// DOUBLE-BUFFERED K/V staging, ONE barrier per iter:
//   barrier (waits stage(j), issued one compute-phase ago) ->
//   issue async stage(j+1) into other buffer -> compute(j).
// The compiler's forced vmcnt(0) drain at each barrier thus waits on loads
// that had a full compute phase in flight -> HBM latency hidden.
// sK/sV/sP chunk-XOR swizzled (2-way max, free). Q frags in registers.
// Fixed-reference softmax: p = exp2(s) raw; scale cancels in O/l.
// LDS 80KB -> 2 blocks/CU.
// ---------------------------------------------------------------------------
__global__ __launch_bounds__(256, 2) void attn_kernel(
    const __bf16* __restrict__ qkv, const __bf16* __restrict__ vt,
    __bf16* __restrict__ O) {
  __shared__ __attribute__((aligned(16))) __bf16 sK[2][64 * 128];  // 32 KB
  __shared__ __attribute__((aligned(16))) __bf16 sV[2][128 * 64];  // 32 KB
  __shared__ __attribute__((aligned(16))) __bf16 sP[4][32 * 64];   // 16 KB

  const int qi = gridDim.x - 1 - blockIdx.x, bh = blockIdx.y;
  const int b = bh >> 4, h = bh & 15;
  const int tid = threadIdx.x, wave = tid >> 6, lane = tid & 63;
  const int quad = lane >> 4, l15 = lane & 15;
  const int sw3 = l15 & 7;

  const long rowQ0 = (long)(b * SS + qi * 128);   // block's first q row
  const int qrow0 = qi * 128 + wave * 32;         // wave's first q row (in S)
  const __bf16* kbase = qkv + (long)(b * SS) * N3 + DD + h * HD;
  const __bf16* vbase = vt + (long)bh * HD * SS;

  // Q fragments in registers: qf[mt][kk] for row-tile mt (rows +mt*16)
  bf16x8 qf[2][4];
#pragma unroll
  for (int mt = 0; mt < 2; ++mt) {
    const __bf16* qp =
        qkv + (rowQ0 + wave * 32 + mt * 16 + l15) * N3 + h * HD + quad * 8;
#pragma unroll
    for (int kk = 0; kk < 4; ++kk) qf[mt][kk] = *(const bf16x8*)(qp + kk * 32);
  }

  f32x4 o_acc[2][8] = {};
  float l_acc[2][4] = {};

  __bf16* sPw = &sP[wave][0];
  const int jn = 2 * qi + 2;  // K tiles 0 .. 2qi+1 (block-uniform)

  // ---- staging helper (wave-uniform LDS dst bases) ----
  auto stageKV = [&](int j, int buf) {
#pragma unroll
    for (int t = 0; t < 4; ++t) {  // K tile 64x128: inst covers 4 rows
      int rbase = wave * 16 + t * 4;            // wave-uniform
      int row = rbase + quad;
      const __bf16* src =
          kbase + (long)(j * 64 + row) * N3 + ((l15 ^ (row & 7)) * 8);
      async16(src, &sK[buf][rbase * 128]);
    }
#pragma unroll
    for (int t = 0; t < 4; ++t) {  // V^T tile 128x64: inst covers 8 rows
      int rbase = wave * 32 + t * 8;            // wave-uniform
      int row = rbase + (lane >> 3);
      const __bf16* src = vbase + (long)row * SS + j * 64 +
                          (((lane & 7) ^ (row & 7)) * 8);
      async16(src, &sV[buf][rbase * 64]);
    }
  };

  stageKV(0, 0);

  for (int j = 0; j < jn; ++j) {
    const int buf = j & 1;
    __syncthreads();                 // waits stage(j) (+ prev compute done)
    if (j + 1 < jn) stageKV(j + 1, buf ^ 1);  // prefetch, hidden by compute(j)

    // wave 0/1 rows are entirely above the diagonal for the final K tile
    const bool active = !((j == 2 * qi + 1) && (wave < 2));
    if (active) {
      const bool needMask =
          ((j == 2 * qi) && (wave < 2)) || ((j == 2 * qi + 1) && (wave >= 2));

      // ---- S = Q K^T : 16 bk reads feed 32 MFMAs ----
      f32x4 sacc[2][4];
#pragma unroll
      for (int nt = 0; nt < 4; ++nt) {
        sacc[0][nt] = (f32x4){0.f, 0.f, 0.f, 0.f};
        sacc[1][nt] = (f32x4){0.f, 0.f, 0.f, 0.f};
#pragma unroll
        for (int kk = 0; kk < 4; ++kk) {
          bf16x8 bk = *(const bf16x8*)
              &sK[buf][(nt * 16 + l15) * 128 + (((kk * 4 + quad) ^ sw3) * 8)];
          sacc[0][nt] = __builtin_amdgcn_mfma_f32_16x16x32_bf16(
              qf[0][kk], bk, sacc[0][nt], 0, 0, 0);
          sacc[1][nt] = __builtin_amdgcn_mfma_f32_16x16x32_bf16(
              qf[1][kk], bk, sacc[1][nt], 0, 0, 0);
        }
      }
      if (needMask) {
#pragma unroll
        for (int mt = 0; mt < 2; ++mt) {
          int rowg0 = qrow0 + mt * 16 + quad * 4;
#pragma unroll
          for (int nt = 0; nt < 4; ++nt) {
            int colg = j * 64 + nt * 16 + l15;
#pragma unroll
            for (int r = 0; r < 4; ++r)
              if (colg > rowg0 + r) sacc[mt][nt][r] = -1e30f;
          }
        }
      }
      // ---- p = exp2(s) -> sP (wave-private), accumulate l per lane ----
#pragma unroll
      for (int mt = 0; mt < 2; ++mt) {
#pragma unroll
        for (int nt = 0; nt < 4; ++nt) {
#pragma unroll
          for (int r = 0; r < 4; ++r) {
            float pv = exp2f(sacc[mt][nt][r]);
            l_acc[mt][r] += pv;
            int prow = mt * 16 + quad * 4 + r;
            int pcol = nt * 16 + l15;
            sPw[prow * 64 + (((pcol >> 3) ^ (prow & 7)) * 8) + (pcol & 7)] =
                (__bf16)pv;
          }
        }
      }
      // ---- O += P V : 4 ap + 16 bv reads feed 32 MFMAs ----
#pragma unroll
      for (int kk = 0; kk < 2; ++kk) {
        bf16x8 ap0 = *(const bf16x8*)
            &sPw[l15 * 64 + (((kk * 4 + quad) ^ sw3) * 8)];
        bf16x8 ap1 = *(const bf16x8*)
            &sPw[(16 + l15) * 64 + (((kk * 4 + quad) ^ sw3) * 8)];
#pragma unroll
        for (int dt = 0; dt < 8; ++dt) {
          bf16x8 bv = *(const bf16x8*)
              &sV[buf][(dt * 16 + l15) * 64 + (((kk * 4 + quad) ^ sw3) * 8)];
          o_acc[0][dt] = __builtin_amdgcn_mfma_f32_16x16x32_bf16(
              ap0, bv, o_acc[0][dt], 0, 0, 0);
          o_acc[1][dt] = __builtin_amdgcn_mfma_f32_16x16x32_bf16(
              ap1, bv, o_acc[1][dt], 0, 0, 0);
        }
      }
    }
  }

  // final l reduction across the 16 lanes of each quad-row, then write O
#pragma unroll
  for (int mt = 0; mt < 2; ++mt) {
    __bf16* obase = O + (rowQ0 + wave * 32 + mt * 16 + quad * 4) * DD + h * HD;
#pragma unroll
    for (int r = 0; r < 4; ++r) {
      float l = l_acc[mt][r];
#pragma unroll
      for (int off = 1; off < 16; off <<= 1) l += __shfl_xor(l, off, 64);
      float inv = 1.0f / l;
#pragma unroll
      for (int dt = 0; dt < 8; ++dt)
        obase[(long)r * DD + dt * 16 + l15] = (__bf16)(o_acc[mt][dt][r] * inv);
    }
  }
}

extern "C" void kernel_launch(void* const* d_in, const int* in_sizes, int n_in,
                              void* d_out, int out_size, void* d_ws,
                              size_t ws_size, hipStream_t stream) {
  const float* x      = (const float*)d_in[0];
  const float* w_qkv  = (const float*)d_in[1];
  const float* b_qkv  = (const float*)d_in[2];
  const float* q_ln_w = (const float*)d_in[3];
  const float* k_ln_w = (const float*)d_in[4];
  const float* w_out  = (const float*)d_in[5];
  const float* b_out  = (const float*)d_in[6];
  float* out = (float*)d_out;

  char* w = (char*)d_ws;
  __bf16* xb    = (__bf16*)(w);
  __bf16* wqkvT = (__bf16*)(w + 25165824L);
  __bf16* woutT = (__bf16*)(w + 50331648L);
  __bf16* qkvb  = (__bf16*)(w + 58720256L);
  __bf16* vtb   = (__bf16*)(w + 134217728L);
  __bf16* atto  = xb;

  cast_bf16_kernel<<<dim3(BS * DD / 2048), 256, 0, stream>>>(x, xb);
  transpose_cast_kernel<<<dim3(N3 / 32, DD / 32), 256, 0, stream>>>(
      w_qkv, wqkvT, DD, N3);
  transpose_cast_kernel<<<dim3(DD / 32, DD / 32), 256, 0, stream>>>(
      w_out, woutT, DD, DD);

  gemm_bt_kernel<__bf16><<<dim3(N3 / 128, BS / 128), 256, 0, stream>>>(
      xb, wqkvT, b_qkv, qkvb, BS, N3, DD);

  rmsnorm_kernel<<<dim3(2 * BS), 256, 0, stream>>>(qkvb, q_ln_w, k_ln_w);

  transpose_v_kernel<<<dim3(SS / 32, HD / 32, BB * HH), 256, 0, stream>>>(
      qkvb, vtb);

  attn_kernel<<<dim3(SS / 128, BB * HH), 256, 0, stream>>>(qkvb, vtb, atto);

  gemm_bt_kernel<float><<<dim3(DD / 128, BS / 128), 256, 0, stream>>>(
      atto, woutT, b_out, out, BS, DD, DD);
}